// Round 11
// baseline (394.710 us; speedup 1.0000x reference)
//
#include <hip/hip_runtime.h>
#include <hip/hip_cooperative_groups.h>

namespace cg = cooperative_groups;

#define G 64
#define C 32
#define D 18432
#define NCH 16              // chunks per group; 1024 blocks total, 4/CU
#define TD (D / NCH)        // 1152 cols per chunk
#define NST (TD / 128)      // 9 k-steps (4 waves x 32 cols)
#define EPS 1e-5f
#define NS_ITERS 5

typedef __attribute__((ext_vector_type(8))) short short8v;
typedef __attribute__((ext_vector_type(4))) float float4v;

__device__ __forceinline__ void split3(float x, unsigned short& h1,
                                       unsigned short& h2, unsigned short& h3) {
    unsigned int u = __float_as_uint(x);
    unsigned int m1 = u & 0xffff0000u;
    float r1 = x - __uint_as_float(m1);
    unsigned int u2 = __float_as_uint(r1);
    unsigned int m2 = u2 & 0xffff0000u;
    float r2 = r1 - __uint_as_float(m2);
    h1 = (unsigned short)(m1 >> 16);
    h2 = (unsigned short)(m2 >> 16);
    h3 = (unsigned short)(__float_as_uint(r2) >> 16);
}

__device__ __forceinline__ void split8(const float4& v0, const float4& v1,
                                       short8v& p1, short8v& p2, short8v& p3,
                                       float& rs) {
    float x[8] = {v0.x, v0.y, v0.z, v0.w, v1.x, v1.y, v1.z, v1.w};
#pragma unroll
    for (int j = 0; j < 8; ++j) {
        unsigned short h1, h2, h3;
        rs += x[j];
        split3(x[j], h1, h2, h3);
        p1[j] = (short)h1; p2[j] = (short)h2; p3[j] = (short)h3;
    }
}

// 6 MFMAs: 3-term split product (terms >= 2^-18 kept -> fp32-grade Gram)
#define MM6(T, A0, A1, A2, B0, B1, B2)                                        \
    T = __builtin_amdgcn_mfma_f32_16x16x32_bf16(A0, B0, T, 0, 0, 0);          \
    T = __builtin_amdgcn_mfma_f32_16x16x32_bf16(A0, B1, T, 0, 0, 0);          \
    T = __builtin_amdgcn_mfma_f32_16x16x32_bf16(A1, B0, T, 0, 0, 0);          \
    T = __builtin_amdgcn_mfma_f32_16x16x32_bf16(A1, B1, T, 0, 0, 0);          \
    T = __builtin_amdgcn_mfma_f32_16x16x32_bf16(A0, B2, T, 0, 0, 0);          \
    T = __builtin_amdgcn_mfma_f32_16x16x32_bf16(A2, B0, T, 0, 0, 0);

// ===========================================================================
// FUSED v2: 1024 blocks x 256 threads (4 blocks/CU = 16 waves/CU, the proven
// R7-k1 occupancy). Phase1 = R7 gram verbatim -> grid.sync -> Phase2 = R9 NS
// verbatim (redundant per block, no tail) -> Phase3 = float2 apply (64-reg
// acc, no spill) on the block's own 1152 cols with W L3-warm.
// ===========================================================================
__global__ __launch_bounds__(256, 4) void fused_all(const float* __restrict__ W,
                                                    float* __restrict__ psum,
                                                    float* __restrict__ prow,
                                                    float* __restrict__ mtb,
                                                    float* __restrict__ vvb,
                                                    float* __restrict__ out) {
    __shared__ float red[4 * 1056 + 4 * C];   // gram planes; reused for NS
    __shared__ float mean[C];
    __shared__ float redw[4];
    __shared__ float normsh;

    const int b    = blockIdx.x;
    const int g    = b >> 4;          // / NCH
    const int ch   = b & 15;          // % NCH
    const int tid  = threadIdx.x;
    const int lane = tid & 63;
    const int wave = tid >> 6;

    // ---------------- phase 1: Gram partial (R7 core, verbatim) ------------
    {
        const int rbase = lane & 15;
        const int koff  = (lane >> 4) * 8;
        const float* Zg = W + (size_t)g * C * D + (size_t)ch * TD;
        const float* p0 = Zg + (size_t)rbase * D + wave * 32 + koff;
        const float* p1 = p0 + (size_t)16 * D;

        float4v acc00 = (float4v)0.f, acc01 = (float4v)0.f;
        float4v acc10 = (float4v)0.f, acc11 = (float4v)0.f;
        float rs0 = 0.f, rs1 = 0.f;

        float4 c00 = *(const float4*)(p0);
        float4 c01 = *(const float4*)(p0 + 4);
        float4 c10 = *(const float4*)(p1);
        float4 c11 = *(const float4*)(p1 + 4);

#pragma unroll 1
        for (int st = 0; st < NST; ++st) {
            float4 n00, n01, n10, n11;
            if (st + 1 < NST) {
                const float* q0 = p0 + (st + 1) * 128;
                const float* q1 = p1 + (st + 1) * 128;
                n00 = *(const float4*)(q0);
                n01 = *(const float4*)(q0 + 4);
                n10 = *(const float4*)(q1);
                n11 = *(const float4*)(q1 + 4);
            }
            short8v fa0, fa1, fa2, fb0, fb1, fb2;
            split8(c00, c01, fa0, fa1, fa2, rs0);
            split8(c10, c11, fb0, fb1, fb2, rs1);

            MM6(acc00, fa0, fa1, fa2, fa0, fa1, fa2)
            MM6(acc01, fa0, fa1, fa2, fb0, fb1, fb2)
            MM6(acc10, fb0, fb1, fb2, fa0, fa1, fa2)
            MM6(acc11, fb0, fb1, fb2, fb0, fb1, fb2)

            c00 = n00; c01 = n01; c10 = n10; c11 = n11;
        }

        rs0 += __shfl_xor(rs0, 16, 64); rs0 += __shfl_xor(rs0, 32, 64);
        rs1 += __shfl_xor(rs1, 16, 64); rs1 += __shfl_xor(rs1, 32, 64);
        if (lane < 16) {
            red[4224 + wave * C + lane]      = rs0;
            red[4224 + wave * C + 16 + lane] = rs1;
        }
        {
            const int rq = (lane >> 4) << 2;   // m89-verified C/D map
            const int cl = lane & 15;
            float* base = red + wave * 1056;
#pragma unroll
            for (int j = 0; j < 4; ++j) {
                base[(rq + j) * 33 + cl]           = acc00[j];
                base[(rq + j) * 33 + 16 + cl]      = acc01[j];
                base[(16 + rq + j) * 33 + cl]      = acc10[j];
                base[(16 + rq + j) * 33 + 16 + cl] = acc11[j];
            }
        }
        __syncthreads();
#pragma unroll
        for (int k = 0; k < 4; ++k) {
            int el = tid + 256 * k;
            int row = el >> 5, col = el & 31;
            int o = row * 33 + col;
            float sv = red[o] + red[1056 + o] + red[2112 + o] + red[3168 + o];
            psum[(size_t)b * 1024 + el] = sv;
        }
        if (tid < C) {
            float s = red[4224 + tid] + red[4224 + C + tid] +
                      red[4224 + 2 * C + tid] + red[4224 + 3 * C + tid];
            prow[(size_t)b * C + tid] = s;
        }
    }

    __threadfence();
    cg::this_grid().sync();
    __syncthreads();

    // ---------------- phase 2: NS (R9 k2 core, redundant x16 per group) ----
    {
        const int e   = tid & 31;
        const int cbq = tid >> 5;
        float* Sm  = red;          // [33] stride
        float* Bm  = red + 1056;
        float* T1m = red + 2112;
        float* T2m = red + 3168;

        float selt[4];
#pragma unroll
        for (int k = 0; k < 4; ++k) {
            int el = tid + 256 * k;
            float s = 0.f;
#pragma unroll
            for (int c2 = 0; c2 < NCH; ++c2)
                s += psum[((size_t)g * NCH + c2) * 1024 + el];
            selt[k] = s;
        }
        if (tid < C) {
            float s = 0.f;
#pragma unroll
            for (int c2 = 0; c2 < NCH; ++c2)
                s += prow[((size_t)g * NCH + c2) * C + tid];
            mean[tid] = s / (float)D;
        }
        __syncthreads();

        float ss = 0.f;
#pragma unroll
        for (int k = 0; k < 4; ++k) {
            int el = tid + 256 * k;
            int c = el >> 5;
            float sv = selt[k] - (float)D * mean[c] * mean[e];
            if (c == e) sv += EPS;
            Sm[c * 33 + e] = sv;
            ss = fmaf(sv, sv, ss);
        }
#pragma unroll
        for (int off = 32; off >= 1; off >>= 1) ss += __shfl_xor(ss, off, 64);
        if ((tid & 63) == 0) redw[tid >> 6] = ss;
        __syncthreads();
        if (tid == 0) normsh = sqrtf(redw[0] + redw[1] + redw[2] + redw[3]);
        __syncthreads();
        const float inv_norm = 1.0f / normsh;
#pragma unroll
        for (int k = 0; k < 4; ++k) {
            int c = cbq + 8 * k;
            Sm[c * 33 + e] *= inv_norm;
            Bm[c * 33 + e] = (c == e) ? 1.f : 0.f;
        }
        __syncthreads();

        for (int it = 0; it < NS_ITERS; ++it) {
#pragma unroll
            for (int k = 0; k < 4; ++k) {
                int c = cbq + 8 * k;
                float s = 0.f;
                for (int kk = 0; kk < C; ++kk)
                    s = fmaf(Bm[c * 33 + kk], Bm[kk * 33 + e], s);
                T1m[c * 33 + e] = s;
            }
            __syncthreads();
#pragma unroll
            for (int k = 0; k < 4; ++k) {
                int c = cbq + 8 * k;
                float s = 0.f;
                for (int kk = 0; kk < C; ++kk)
                    s = fmaf(T1m[c * 33 + kk], Bm[kk * 33 + e], s);
                T2m[c * 33 + e] = s;
            }
            __syncthreads();
            float pv[4];
#pragma unroll
            for (int k = 0; k < 4; ++k) {
                int c = cbq + 8 * k;
                float s = 0.f;
                for (int kk = 0; kk < C; ++kk)
                    s = fmaf(T2m[c * 33 + kk], Sm[kk * 33 + e], s);
                pv[k] = s;
            }
#pragma unroll
            for (int k = 0; k < 4; ++k) {
                int c = cbq + 8 * k;
                Bm[c * 33 + e] = 1.5f * Bm[c * 33 + e] - 0.5f * pv[k];
            }
            __syncthreads();
        }

        const float invs = 1.0f / sqrtf(normsh);
#pragma unroll
        for (int k = 0; k < 4; ++k) {
            int c = cbq + 8 * k;
            mtb[(size_t)b * 1024 + e * C + c] = Bm[c * 33 + e] * invs;
        }
        if (tid < C) {
            float s = 0.f;
            for (int ee = 0; ee < C; ++ee)
                s = fmaf(Bm[tid * 33 + ee] * invs, mean[ee], s);
            vvb[(size_t)b * C + tid] = s;
        }
    }
    __syncthreads();   // drains vmcnt -> own-block mtb/vvb stores in L2

    // ---------------- phase 3: apply on this block's 1152 cols -------------
    {
        const float* Mg = mtb + (size_t)b * 1024;   // private -> s_load path
        const float* vg = vvb + (size_t)b * C;
        const float* Zb = W + (size_t)g * C * D + (size_t)ch * TD;
        float*       Ob = out + (size_t)g * C * D + (size_t)ch * TD;

#pragma unroll 1
        for (int p = 0; p < 3; ++p) {
            const int u = tid + p * 256;            // float2 unit, 576 per block
            if (u < TD / 2) {
                const float* Zc = Zb + (size_t)u * 2;
                float2 acc[C];
#pragma unroll
                for (int r = 0; r < C; ++r) acc[r] = make_float2(0.f, 0.f);
#pragma unroll 4
                for (int e2 = 0; e2 < C; ++e2) {
                    float2 z = *(const float2*)(Zc + (size_t)e2 * D);
#pragma unroll
                    for (int r = 0; r < C; ++r) {
                        float m = Mg[e2 * C + r];   // wave-uniform
                        acc[r].x = fmaf(m, z.x, acc[r].x);
                        acc[r].y = fmaf(m, z.y, acc[r].y);
                    }
                }
                float* Oc = Ob + (size_t)u * 2;
#pragma unroll
                for (int r = 0; r < C; ++r) {
                    float vr = vg[r];
                    float2 o = make_float2(acc[r].x - vr, acc[r].y - vr);
                    *(float2*)(Oc + (size_t)r * D) = o;
                }
            }
        }
    }
}

// ===========================================================================
// Fallback: R9's three kernels, verbatim (known-pass ~95 us)
// ===========================================================================
__global__ __launch_bounds__(256) void k1_gram(const float* __restrict__ W,
                                               float* __restrict__ psum,
                                               float* __restrict__ prow) {
    __shared__ float red[4 * 1056 + 4 * C];
    const int ch   = blockIdx.x;
    const int g    = blockIdx.y;
    const int bid  = g * NCH + ch;
    const int tid  = threadIdx.x;
    const int lane = tid & 63;
    const int wave = tid >> 6;
    const int rbase = lane & 15;
    const int koff  = (lane >> 4) * 8;
    const float* Zg = W + (size_t)g * C * D + (size_t)ch * TD;
    const float* p0 = Zg + (size_t)rbase * D + wave * 32 + koff;
    const float* p1 = p0 + (size_t)16 * D;
    float4v acc00 = (float4v)0.f, acc01 = (float4v)0.f;
    float4v acc10 = (float4v)0.f, acc11 = (float4v)0.f;
    float rs0 = 0.f, rs1 = 0.f;
    float4 c00 = *(const float4*)(p0);
    float4 c01 = *(const float4*)(p0 + 4);
    float4 c10 = *(const float4*)(p1);
    float4 c11 = *(const float4*)(p1 + 4);
#pragma unroll 1
    for (int st = 0; st < NST; ++st) {
        float4 n00, n01, n10, n11;
        if (st + 1 < NST) {
            const float* q0 = p0 + (st + 1) * 128;
            const float* q1 = p1 + (st + 1) * 128;
            n00 = *(const float4*)(q0);
            n01 = *(const float4*)(q0 + 4);
            n10 = *(const float4*)(q1);
            n11 = *(const float4*)(q1 + 4);
        }
        short8v fa0, fa1, fa2, fb0, fb1, fb2;
        split8(c00, c01, fa0, fa1, fa2, rs0);
        split8(c10, c11, fb0, fb1, fb2, rs1);
        MM6(acc00, fa0, fa1, fa2, fa0, fa1, fa2)
        MM6(acc01, fa0, fa1, fa2, fb0, fb1, fb2)
        MM6(acc10, fb0, fb1, fb2, fa0, fa1, fa2)
        MM6(acc11, fb0, fb1, fb2, fb0, fb1, fb2)
        c00 = n00; c01 = n01; c10 = n10; c11 = n11;
    }
    rs0 += __shfl_xor(rs0, 16, 64); rs0 += __shfl_xor(rs0, 32, 64);
    rs1 += __shfl_xor(rs1, 16, 64); rs1 += __shfl_xor(rs1, 32, 64);
    if (lane < 16) {
        red[4224 + wave * C + lane]      = rs0;
        red[4224 + wave * C + 16 + lane] = rs1;
    }
    {
        const int rq = (lane >> 4) << 2;
        const int cl = lane & 15;
        float* base = red + wave * 1056;
#pragma unroll
        for (int j = 0; j < 4; ++j) {
            base[(rq + j) * 33 + cl]           = acc00[j];
            base[(rq + j) * 33 + 16 + cl]      = acc01[j];
            base[(16 + rq + j) * 33 + cl]      = acc10[j];
            base[(16 + rq + j) * 33 + 16 + cl] = acc11[j];
        }
    }
    __syncthreads();
#pragma unroll
    for (int k = 0; k < 4; ++k) {
        int el = tid + 256 * k;
        int row = el >> 5, col = el & 31;
        int o = row * 33 + col;
        float sv = red[o] + red[1056 + o] + red[2112 + o] + red[3168 + o];
        psum[(size_t)bid * (C * C) + el] = sv;
    }
    if (tid < C) {
        float s = red[4224 + tid] + red[4224 + C + tid] +
                  red[4224 + 2 * C + tid] + red[4224 + 3 * C + tid];
        prow[(size_t)bid * C + tid] = s;
    }
}

__global__ __launch_bounds__(256) void k2_ns(const float* __restrict__ psum,
                                             const float* __restrict__ prow,
                                             float* __restrict__ MT,
                                             float* __restrict__ vout) {
    __shared__ float S[C][C + 1];
    __shared__ float B[C][C + 1];
    __shared__ float T1[C][C + 1];
    __shared__ float T2[C][C + 1];
    __shared__ float mean[C];
    __shared__ float redw[4];
    __shared__ float normsh;
    const int g   = blockIdx.x;
    const int tid = threadIdx.x;
    const int e   = tid & 31;
    const int cbq = tid >> 5;
    float selt[4];
#pragma unroll
    for (int k = 0; k < 4; ++k) {
        int el = tid + 256 * k;
        float s = 0.f;
#pragma unroll
        for (int ch = 0; ch < NCH; ++ch)
            s += psum[((size_t)g * NCH + ch) * (C * C) + el];
        selt[k] = s;
    }
    if (tid < C) {
        float s = 0.f;
#pragma unroll
        for (int ch = 0; ch < NCH; ++ch)
            s += prow[((size_t)g * NCH + ch) * C + tid];
        mean[tid] = s / (float)D;
    }
    __syncthreads();
    float ss = 0.f;
#pragma unroll
    for (int k = 0; k < 4; ++k) {
        int el = tid + 256 * k;
        int c = el >> 5;
        float sv = selt[k] - (float)D * mean[c] * mean[e];
        if (c == e) sv += EPS;
        S[c][e] = sv;
        ss = fmaf(sv, sv, ss);
    }
#pragma unroll
    for (int off = 32; off >= 1; off >>= 1) ss += __shfl_xor(ss, off, 64);
    if ((tid & 63) == 0) redw[tid >> 6] = ss;
    __syncthreads();
    if (tid == 0) normsh = sqrtf(redw[0] + redw[1] + redw[2] + redw[3]);
    __syncthreads();
    const float inv_norm = 1.0f / normsh;
#pragma unroll
    for (int k = 0; k < 4; ++k) {
        int c = cbq + 8 * k;
        S[c][e] *= inv_norm;
        B[c][e] = (c == e) ? 1.f : 0.f;
    }
    __syncthreads();
    for (int it = 0; it < NS_ITERS; ++it) {
#pragma unroll
        for (int k = 0; k < 4; ++k) {
            int c = cbq + 8 * k;
            float s = 0.f;
            for (int kk = 0; kk < C; ++kk)
                s = fmaf(B[c][kk], B[kk][e], s);
            T1[c][e] = s;
        }
        __syncthreads();
#pragma unroll
        for (int k = 0; k < 4; ++k) {
            int c = cbq + 8 * k;
            float s = 0.f;
            for (int kk = 0; kk < C; ++kk)
                s = fmaf(T1[c][kk], B[kk][e], s);
            T2[c][e] = s;
        }
        __syncthreads();
        float pv[4];
#pragma unroll
        for (int k = 0; k < 4; ++k) {
            int c = cbq + 8 * k;
            float s = 0.f;
            for (int kk = 0; kk < C; ++kk)
                s = fmaf(T2[c][kk], S[kk][e], s);
            pv[k] = s;
        }
#pragma unroll
        for (int k = 0; k < 4; ++k) {
            int c = cbq + 8 * k;
            B[c][e] = 1.5f * B[c][e] - 0.5f * pv[k];
        }
        __syncthreads();
    }
    const float invs = 1.0f / sqrtf(normsh);
#pragma unroll
    for (int k = 0; k < 4; ++k) {
        int c = cbq + 8 * k;
        MT[(size_t)g * (C * C) + e * C + c] = B[c][e] * invs;
    }
    if (tid < C) {
        float s = 0.f;
        for (int ee = 0; ee < C; ++ee)
            s = fmaf(B[tid][ee] * invs, mean[ee], s);
        vout[(size_t)g * C + tid] = s;
    }
}

__global__ __launch_bounds__(256) void k3_apply(const float* __restrict__ W,
                                                const float* __restrict__ MT,
                                                const float* __restrict__ vv,
                                                float* __restrict__ out) {
    const int bpg = D / 1024;
    const int g   = blockIdx.x / bpg;
    const int cbk = blockIdx.x % bpg;
    const int d0  = cbk * 1024 + (int)threadIdx.x * 4;
    const float* Zg = W + (size_t)g * C * D + d0;
    const float* Mg = MT + (size_t)g * (C * C);
    float4 acc[C];
#pragma unroll
    for (int r = 0; r < C; ++r) acc[r] = make_float4(0.f, 0.f, 0.f, 0.f);
#pragma unroll 4
    for (int e = 0; e < C; ++e) {
        float4 z = *(const float4*)(Zg + (size_t)e * D);
#pragma unroll
        for (int r = 0; r < C; ++r) {
            float m = Mg[e * C + r];
            acc[r].x = fmaf(m, z.x, acc[r].x);
            acc[r].y = fmaf(m, z.y, acc[r].y);
            acc[r].z = fmaf(m, z.z, acc[r].z);
            acc[r].w = fmaf(m, z.w, acc[r].w);
        }
    }
    float* Og = out + (size_t)g * C * D + d0;
#pragma unroll
    for (int r = 0; r < C; ++r) {
        float vr = vv[g * C + r];
        float4 o = make_float4(acc[r].x - vr, acc[r].y - vr,
                               acc[r].z - vr, acc[r].w - vr);
        *(float4*)(Og + (size_t)r * D) = o;
    }
}

extern "C" void kernel_launch(void* const* d_in, const int* in_sizes, int n_in,
                              void* d_out, int out_size, void* d_ws, size_t ws_size,
                              hipStream_t stream) {
    const float* w = (const float*)d_in[0];
    float* out = (float*)d_out;

    const int NB = G * NCH;   // 1024 blocks
    const size_t fused_need = (size_t)NB * (1024 + 32) * 2 * sizeof(float);
    bool done = false;
    if (ws_size >= fused_need) {
        float* psum = (float*)d_ws;                     // NB*1024
        float* prow = psum + (size_t)NB * 1024;         // NB*32
        float* mtb  = prow + (size_t)NB * 32;           // NB*1024
        float* vvb  = mtb + (size_t)NB * 1024;          // NB*32
        void* args[] = {(void*)&w, (void*)&psum, (void*)&prow,
                        (void*)&mtb, (void*)&vvb, (void*)&out};
        hipError_t err = hipLaunchCooperativeKernel((void*)fused_all, dim3(NB),
                                                    dim3(256), args, 0, stream);
        done = (err == hipSuccess);
    }
    if (!done) {
        float* psum = (float*)d_ws;
        float* prow = psum + (size_t)(G * NCH) * (C * C);
        float* MT   = prow + (size_t)(G * NCH) * C;
        float* vv   = MT + (size_t)G * (C * C);
        k1_gram<<<dim3(NCH, G), 256, 0, stream>>>(w, psum, prow);
        k2_ns<<<G, 256, 0, stream>>>(psum, prow, MT, vv);
        k3_apply<<<G * (D / 1024), 256, 0, stream>>>(w, MT, vv, out);
    }
}

// Round 13
// 94.639 us; speedup vs baseline: 4.1707x; 4.1707x over previous
//
#include <hip/hip_runtime.h>

#define G 64
#define C 32
#define D 18432
#define NCH 16          // chunks per group: 1024 blocks = 4/CU exact
#define TD (D / NCH)    // 1152 cols per chunk
#define NST (TD / 128)  // 9 iterations (4 waves x 32 k-cols each)
#define EPS 1e-5f
#define NS_ITERS 5

typedef __attribute__((ext_vector_type(8))) short short8v;
typedef __attribute__((ext_vector_type(4))) float float4v;

__device__ __forceinline__ void split3(float x, unsigned short& h1,
                                       unsigned short& h2, unsigned short& h3) {
    unsigned int u = __float_as_uint(x);
    unsigned int m1 = u & 0xffff0000u;
    float r1 = x - __uint_as_float(m1);
    unsigned int u2 = __float_as_uint(r1);
    unsigned int m2 = u2 & 0xffff0000u;
    float r2 = r1 - __uint_as_float(m2);
    h1 = (unsigned short)(m1 >> 16);
    h2 = (unsigned short)(m2 >> 16);
    h3 = (unsigned short)(__float_as_uint(r2) >> 16);
}

// split 8 fp32 (two float4) into three bf16x8 fragments, accumulate row sum
__device__ __forceinline__ void split8(const float4& v0, const float4& v1,
                                       short8v& p1, short8v& p2, short8v& p3,
                                       float& rs) {
    float x[8] = {v0.x, v0.y, v0.z, v0.w, v1.x, v1.y, v1.z, v1.w};
#pragma unroll
    for (int j = 0; j < 8; ++j) {
        unsigned short h1, h2, h3;
        rs += x[j];
        split3(x[j], h1, h2, h3);
        p1[j] = (short)h1; p2[j] = (short)h2; p3[j] = (short)h3;
    }
}

// ---------------------------------------------------------------------------
// K1: LDS-FREE partial Gram P = Z_chunk * Z_chunk^T via bf16 MFMA (3-term
//     split, fp32-grade). Lane l's MFMA fragment (rows l&15 / +16, k-slice
//     (l>>4)*8) IS a coalesced global load -> no LDS staging, no barriers in
//     the K-loop; loads pipeline freely across iterations via vmcnt.
//     grid = (NCH, G), block = 256 (4 waves, each owns 32 k-cols per iter)
// ---------------------------------------------------------------------------
__global__ __launch_bounds__(256) void k1_gram(const float* __restrict__ W,
                                               float* __restrict__ psum,
                                               float* __restrict__ prow) {
    __shared__ float red[4 * 1056 + 4 * C];   // Gram partials + rowsum partials

    const int ch   = blockIdx.x;
    const int g    = blockIdx.y;
    const int bid  = g * NCH + ch;
    const int tid  = threadIdx.x;
    const int lane = tid & 63;
    const int wave = tid >> 6;

    const int rbase = lane & 15;          // fragment row within 16-half
    const int koff  = (lane >> 4) * 8;    // k-slice within 32-col step

    const float* Zg   = W + (size_t)g * C * D + (size_t)ch * TD;
    const float* p0   = Zg + (size_t)rbase * D + wave * 32 + koff;        // rows 0..15
    const float* p1   = p0 + (size_t)16 * D;                              // rows 16..31

    float4v acc[2][2];
#pragma unroll
    for (int a = 0; a < 2; ++a)
#pragma unroll
        for (int b = 0; b < 2; ++b) acc[a][b] = (float4v)0.f;
    float rs0 = 0.f, rs1 = 0.f;

    float4 c00 = *(const float4*)(p0);
    float4 c01 = *(const float4*)(p0 + 4);
    float4 c10 = *(const float4*)(p1);
    float4 c11 = *(const float4*)(p1 + 4);

#pragma unroll
    for (int st = 0; st < NST; ++st) {
        float4 n00, n01, n10, n11;
        if (st + 1 < NST) {
            n00 = *(const float4*)(p0 + (st + 1) * 128);
            n01 = *(const float4*)(p0 + (st + 1) * 128 + 4);
            n10 = *(const float4*)(p1 + (st + 1) * 128);
            n11 = *(const float4*)(p1 + (st + 1) * 128 + 4);
        }
        short8v fa[3], fb[3];
        split8(c00, c01, fa[0], fa[1], fa[2], rs0);
        split8(c10, c11, fb[0], fb[1], fb[2], rs1);

        short8v* fr[2] = {fa, fb};
#pragma unroll
        for (int a = 0; a < 2; ++a)
#pragma unroll
            for (int b = 0; b < 2; ++b) {
                float4v t = acc[a][b];
                t = __builtin_amdgcn_mfma_f32_16x16x32_bf16(fr[a][0], fr[b][0], t, 0, 0, 0);
                t = __builtin_amdgcn_mfma_f32_16x16x32_bf16(fr[a][0], fr[b][1], t, 0, 0, 0);
                t = __builtin_amdgcn_mfma_f32_16x16x32_bf16(fr[a][1], fr[b][0], t, 0, 0, 0);
                t = __builtin_amdgcn_mfma_f32_16x16x32_bf16(fr[a][1], fr[b][1], t, 0, 0, 0);
                t = __builtin_amdgcn_mfma_f32_16x16x32_bf16(fr[a][0], fr[b][2], t, 0, 0, 0);
                t = __builtin_amdgcn_mfma_f32_16x16x32_bf16(fr[a][2], fr[b][0], t, 0, 0, 0);
                acc[a][b] = t;
            }
        c00 = n00; c01 = n01; c10 = n10; c11 = n11;
    }

    // rowsum: lanes {l, l+16, l+32, l+48} hold partials of the same row
    rs0 += __shfl_xor(rs0, 16, 64); rs0 += __shfl_xor(rs0, 32, 64);
    rs1 += __shfl_xor(rs1, 16, 64); rs1 += __shfl_xor(rs1, 32, 64);
    if (lane < 16) {
        red[4224 + wave * C + lane]      = rs0;
        red[4224 + wave * C + 16 + lane] = rs1;
    }

    // Gram partials -> LDS (m89-verified C/D map: col=lane&15, row=(lane>>4)*4+j)
#pragma unroll
    for (int a = 0; a < 2; ++a)
#pragma unroll
        for (int b = 0; b < 2; ++b)
#pragma unroll
            for (int j = 0; j < 4; ++j) {
                int row = 16 * a + ((lane >> 4) << 2) + j;
                int col = 16 * b + (lane & 15);
                red[wave * 1056 + row * 33 + col] = acc[a][b][j];
            }
    __syncthreads();

#pragma unroll
    for (int k = 0; k < 4; ++k) {
        int el = tid + 256 * k;
        int row = el >> 5, col = el & 31;
        int o = row * 33 + col;
        float sv = red[o] + red[1056 + o] + red[2112 + o] + red[3168 + o];
        psum[(size_t)bid * (C * C) + el] = sv;
    }
    if (tid < C) {
        float s = red[4224 + tid] + red[4224 + C + tid] +
                  red[4224 + 2 * C + tid] + red[4224 + 3 * C + tid];
        prow[(size_t)bid * C + tid] = s;
    }
}

// ---------------------------------------------------------------------------
// K2: per group: S = sum(partials) - D*m*m^T + EPS*I; Frobenius-normalize;
//     5 Newton-Schulz iterations; emit M^T and v = M*m.  (compile-time NCH)
// ---------------------------------------------------------------------------
__global__ __launch_bounds__(256) void k2_ns(const float* __restrict__ psum,
                                             const float* __restrict__ prow,
                                             float* __restrict__ MT,
                                             float* __restrict__ vout) {
    __shared__ float S[C][C + 1];
    __shared__ float B[C][C + 1];
    __shared__ float T1[C][C + 1];
    __shared__ float T2[C][C + 1];
    __shared__ float mean[C];
    __shared__ float redw[4];
    __shared__ float normsh;

    const int g   = blockIdx.x;
    const int tid = threadIdx.x;
    const int e   = tid & 31;
    const int cbq = tid >> 5;

    float selt[4];
#pragma unroll
    for (int k = 0; k < 4; ++k) {
        int el = tid + 256 * k;
        float s = 0.f;
#pragma unroll
        for (int ch = 0; ch < NCH; ++ch)
            s += psum[((size_t)g * NCH + ch) * (C * C) + el];
        selt[k] = s;
    }
    if (tid < C) {
        float s = 0.f;
#pragma unroll
        for (int ch = 0; ch < NCH; ++ch)
            s += prow[((size_t)g * NCH + ch) * C + tid];
        mean[tid] = s / (float)D;
    }
    __syncthreads();

    float ss = 0.f;
#pragma unroll
    for (int k = 0; k < 4; ++k) {
        int el = tid + 256 * k;
        int c = el >> 5;
        float sv = selt[k] - (float)D * mean[c] * mean[e];
        if (c == e) sv += EPS;
        S[c][e] = sv;
        ss = fmaf(sv, sv, ss);
    }
#pragma unroll
    for (int off = 32; off >= 1; off >>= 1) ss += __shfl_xor(ss, off, 64);
    if ((tid & 63) == 0) redw[tid >> 6] = ss;
    __syncthreads();
    if (tid == 0) normsh = sqrtf(redw[0] + redw[1] + redw[2] + redw[3]);
    __syncthreads();
    const float inv_norm = 1.0f / normsh;
#pragma unroll
    for (int k = 0; k < 4; ++k) {
        int c = cbq + 8 * k;
        S[c][e] *= inv_norm;
        B[c][e] = (c == e) ? 1.f : 0.f;
    }
    __syncthreads();

    for (int it = 0; it < NS_ITERS; ++it) {
#pragma unroll
        for (int k = 0; k < 4; ++k) {
            int c = cbq + 8 * k;
            float s = 0.f;
            for (int kk = 0; kk < C; ++kk)
                s = fmaf(B[c][kk], B[kk][e], s);
            T1[c][e] = s;
        }
        __syncthreads();
#pragma unroll
        for (int k = 0; k < 4; ++k) {
            int c = cbq + 8 * k;
            float s = 0.f;
            for (int kk = 0; kk < C; ++kk)
                s = fmaf(T1[c][kk], B[kk][e], s);
            T2[c][e] = s;
        }
        __syncthreads();
        float pv[4];
#pragma unroll
        for (int k = 0; k < 4; ++k) {
            int c = cbq + 8 * k;
            float s = 0.f;
            for (int kk = 0; kk < C; ++kk)
                s = fmaf(T2[c][kk], S[kk][e], s);
            pv[k] = s;
        }
#pragma unroll
        for (int k = 0; k < 4; ++k) {
            int c = cbq + 8 * k;
            B[c][e] = 1.5f * B[c][e] - 0.5f * pv[k];
        }
        __syncthreads();
    }

    const float invs = 1.0f / sqrtf(normsh);
#pragma unroll
    for (int k = 0; k < 4; ++k) {
        int c = cbq + 8 * k;
        MT[(size_t)g * (C * C) + e * C + c] = B[c][e] * invs;
    }
    if (tid < C) {
        float s = 0.f;
        for (int ee = 0; ee < C; ++ee)
            s = fmaf(B[tid][ee] * invs, mean[ee], s);
        vout[(size_t)g * C + tid] = s;
    }
}

// ---------------------------------------------------------------------------
// K3: W_out = M * Z - v * 1^T   (per group), 2 cols per thread (float2)
// ---------------------------------------------------------------------------
__global__ __launch_bounds__(256) void k3_apply(const float* __restrict__ W,
                                                const float* __restrict__ MT,
                                                const float* __restrict__ vv,
                                                float* __restrict__ out) {
    const int blocksPerGroup = D / 512;     // 36
    const int g   = blockIdx.x / blocksPerGroup;
    const int cbk = blockIdx.x % blocksPerGroup;
    const int d0  = cbk * 512 + (int)threadIdx.x * 2;
    const float* Zg = W + (size_t)g * C * D + d0;
    const float* Mg = MT + (size_t)g * (C * C);

    float accx[C], accy[C];
#pragma unroll
    for (int r = 0; r < C; ++r) { accx[r] = 0.f; accy[r] = 0.f; }

    for (int e = 0; e < C; ++e) {
        float2 z = *(const float2*)(Zg + (size_t)e * D);
#pragma unroll
        for (int r = 0; r < C; ++r) {
            float m = Mg[e * C + r];   // wave-uniform -> scalar load
            accx[r] = fmaf(m, z.x, accx[r]);
            accy[r] = fmaf(m, z.y, accy[r]);
        }
    }

    float* Og = out + (size_t)g * C * D + d0;
#pragma unroll
    for (int r = 0; r < C; ++r) {
        float vr = vv[g * C + r];      // wave-uniform
        float2 o = make_float2(accx[r] - vr, accy[r] - vr);
        *(float2*)(Og + (size_t)r * D) = o;
    }
}

extern "C" void kernel_launch(void* const* d_in, const int* in_sizes, int n_in,
                              void* d_out, int out_size, void* d_ws, size_t ws_size,
                              hipStream_t stream) {
    const float* w = (const float*)d_in[0];
    float* out = (float*)d_out;

    float* psum = (float*)d_ws;                          // G*NCH*1024 floats (4.2 MB)
    float* prow = psum + (size_t)(G * NCH) * (C * C);    // G*NCH*32
    float* MT   = prow + (size_t)(G * NCH) * C;          // G*1024
    float* vv   = MT   + (size_t)G * (C * C);            // G*32

    k1_gram<<<dim3(NCH, G), 256, 0, stream>>>(w, psum, prow);
    k2_ns  <<<G,            256, 0, stream>>>(psum, prow, MT, vv);
    k3_apply<<<G * (D / 512), 256, 0, stream>>>(w, MT, vv, out);
}